// Round 5
// baseline (354.692 us; speedup 1.0000x reference)
//
#include <hip/hip_runtime.h>
#include <hip/hip_cooperative_groups.h>

namespace cg = cooperative_groups;

// ---------------------------------------------------------------------------
// Conv2DQwenRMSNorm: y = x @ W^T, W = mean_l(conv_w); RMSNorm(y)*norm_w.
// B=4,S=4096 -> M=16384; H=1024 (N=K).
//
// R8: graph-level accounting showed gemm=64us + wprep<=63us but total=219us
// => ~90us+ of inter-dispatch gap / launch overhead. Fuse everything into ONE
// cooperative dispatch:
//  phase 1: W = mean_l(conv_w) -> bf16 frag-major Wf (all 256 blocks help)
//  __threadfence() + grid.sync()  (device-scope release covers XCD L2s)
//  phase 2: R6's sectioned-pipeline GEMM + fused RMSNorm (64.0us, proven)
// 256 blocks x 512 thr, 128KB LDS = 1 block/CU, all co-resident (coop-legal).
// ---------------------------------------------------------------------------

using bf16x8 = __attribute__((ext_vector_type(8))) short;
using f32x16 = __attribute__((ext_vector_type(16))) float;
using f32x4  = __attribute__((ext_vector_type(4))) float;

#define NDIM 1024
#define MTILE 64

__device__ __forceinline__ unsigned short f2bf(float f) {
    unsigned u = __float_as_uint(f);
    u += 0x7fffu + ((u >> 16) & 1u);          // RNE
    return (unsigned short)(u >> 16);
}

__global__ __launch_bounds__(512, 2) void fused_kernel(
        const float* __restrict__ x, const float* __restrict__ cw,
        const float* __restrict__ nw, float* __restrict__ out,
        unsigned short* __restrict__ Wf) {
    __shared__ short lAf[MTILE * NDIM];              // 128 KB, frag-major
    __shared__ float rowss[MTILE];

    const int tid  = threadIdx.x;

    // ================= phase 1: W = mean_l conv_w -> Wf =================
    {
        const int g = blockIdx.x * 512 + tid;        // 0..131071
#pragma unroll
        for (int rep = 0; rep < 2; ++rep) {
            const int idx = g + rep * 131072;        // 0..262143
            const int o   = idx >> 8;                // row 0..1023
            const int q   = idx & 255;               // float4 index in row
            const float* p = cw + (size_t)o * NDIM + (q << 2);
            f32x4 s = {0.f, 0.f, 0.f, 0.f};
#pragma unroll
            for (int l = 0; l < 20; ++l)
                s += *(const f32x4*)(p + (size_t)l * (NDIM * NDIM));
            const float sc = 0.05f;                  // 1/L
            ushort4 o4;
            o4.x = f2bf(s[0] * sc); o4.y = f2bf(s[1] * sc);
            o4.z = f2bf(s[2] * sc); o4.w = f2bf(s[3] * sc);
            const int ct  = o >> 5, ml = o & 31;
            const int k16 = q >> 2, h = (q >> 1) & 1, half = q & 1;
            *(ushort4*)((char*)Wf + (((ct << 6) + k16) << 10) +
                        (((h << 5) + ml) << 4) + (half << 3)) = o4;
        }
        __threadfence();                             // device-scope release
    }
    cg::this_grid().sync();

    // ================= phase 2: GEMM + fused RMSNorm (R6) =================
    const int wv   = tid >> 6;                       // 0..7
    const int lane = tid & 63;
    const int ml   = lane & 31;
    const int h    = lane >> 5;
    const int row0 = blockIdx.x * MTILE;
    const int phase = (blockIdx.x * 37) & 15;        // per-chunk L2 decorrelation

    if (tid < MTILE) rowss[tid] = 0.f;

    // staging geometry (all 512 threads): row = tid>>3, 8-elem cols by tid&7
    const int row = tid >> 3;                        // 0..63
    const int rt  = row >> 5, rml = row & 31;
    const float* xr = x + (size_t)(row0 + row) * NDIM;
    const int kbase = (tid & 7) << 3;

    // B bases: wave wv owns column-tiles ct = wv*4 .. wv*4+3
    const char* bB[4];
#pragma unroll
    for (int c = 0; c < 4; ++c)
        bB[c] = (const char*)Wf + ((((wv << 2) + c) << 6) << 10) + (lane << 4);

    // warm B FIFO (depth 2) for i = 0,1
    bf16x8 bfr[2][4];
#pragma unroll
    for (int d = 0; d < 2; ++d) {
        const int k16 = (d + phase) & 15;            // section 0
#pragma unroll
        for (int cc = 0; cc < 4; ++cc)
            bfr[d][cc] = *(const bf16x8*)(bB[cc] + (k16 << 10));
    }

    // prologue: stage chunk 0 only (64 rows x 256 k, fp32->bf16)
#pragma unroll
    for (int it = 0; it < 4; ++it) {
        const int k0 = kbase + (it << 6);
        f32x4 v0 = __builtin_nontemporal_load((const f32x4*)(xr + k0));
        f32x4 v1 = __builtin_nontemporal_load((const f32x4*)(xr + k0 + 4));
        bf16x8 c8;
        c8[0] = (short)f2bf(v0[0]); c8[1] = (short)f2bf(v0[1]);
        c8[2] = (short)f2bf(v0[2]); c8[3] = (short)f2bf(v0[3]);
        c8[4] = (short)f2bf(v1[0]); c8[5] = (short)f2bf(v1[1]);
        c8[6] = (short)f2bf(v1[2]); c8[7] = (short)f2bf(v1[3]);
        const int k16 = k0 >> 4, hh = (k0 >> 3) & 1;
        const int slot = ((hh << 5) + rml) ^ (k16 & 7);
        *(bf16x8*)((char*)lAf + (((rt << 6) + k16) << 10) + (slot << 4)) = c8;
    }
    __syncthreads();

    f32x16 acc[2][4];
#pragma unroll
    for (int tr = 0; tr < 2; ++tr)
#pragma unroll
        for (int tc = 0; tc < 4; ++tc)
#pragma unroll
            for (int r = 0; r < 16; ++r) acc[tr][tc][r] = 0.f;

    bf16x8 af[2][2];

    // pipelined K loop: 4 sections x 16 iters; section c computes chunk c
    // while staging chunk c+1
#pragma unroll
    for (int c = 0; c < 4; ++c) {
        f32x4 g0[4], g1[4];
        if (c < 3) {
#pragma unroll
            for (int it = 0; it < 4; ++it) {
                const int k0 = kbase + ((((c + 1) << 2) + it) << 6);
                g0[it] = __builtin_nontemporal_load((const f32x4*)(xr + k0));
                g1[it] = __builtin_nontemporal_load((const f32x4*)(xr + k0 + 4));
            }
        }
        // A warm for j = 0,1 of this section
#pragma unroll
        for (int d = 0; d < 2; ++d) {
            const int k16 = (c << 4) + ((d + phase) & 15);
#pragma unroll
            for (int tr = 0; tr < 2; ++tr)
                af[d][tr] = *(const bf16x8*)((const char*)lAf +
                            (((tr << 6) + k16) << 10) + ((lane ^ (k16 & 7)) << 4));
        }

#pragma unroll
        for (int j = 0; j < 16; ++j) {
            const int i  = (c << 4) + j;
            const int ab = j & 1, bb = i & 1;
            __builtin_amdgcn_s_setprio(1);
            acc[0][0] = __builtin_amdgcn_mfma_f32_32x32x16_bf16(af[ab][0], bfr[bb][0], acc[0][0], 0, 0, 0);
            acc[0][1] = __builtin_amdgcn_mfma_f32_32x32x16_bf16(af[ab][0], bfr[bb][1], acc[0][1], 0, 0, 0);
            acc[0][2] = __builtin_amdgcn_mfma_f32_32x32x16_bf16(af[ab][0], bfr[bb][2], acc[0][2], 0, 0, 0);
            acc[0][3] = __builtin_amdgcn_mfma_f32_32x32x16_bf16(af[ab][0], bfr[bb][3], acc[0][3], 0, 0, 0);
            acc[1][0] = __builtin_amdgcn_mfma_f32_32x32x16_bf16(af[ab][1], bfr[bb][0], acc[1][0], 0, 0, 0);
            acc[1][1] = __builtin_amdgcn_mfma_f32_32x32x16_bf16(af[ab][1], bfr[bb][1], acc[1][1], 0, 0, 0);
            acc[1][2] = __builtin_amdgcn_mfma_f32_32x32x16_bf16(af[ab][1], bfr[bb][2], acc[1][2], 0, 0, 0);
            acc[1][3] = __builtin_amdgcn_mfma_f32_32x32x16_bf16(af[ab][1], bfr[bb][3], acc[1][3], 0, 0, 0);
            __builtin_amdgcn_s_setprio(0);
            // B refill (consume-then-refill, distance 2, crosses sections)
            if (i + 2 < 64) {
                const int i2 = i + 2;
                const int k16n = (i2 & ~15) + (((i2 & 15) + phase) & 15);
#pragma unroll
                for (int cc = 0; cc < 4; ++cc)
                    bfr[bb][cc] = *(const bf16x8*)(bB[cc] + (k16n << 10));
            }
            // A refill (distance 2, within section only)
            if (j + 2 < 16) {
                const int k16n = (c << 4) + (((j + 2) + phase) & 15);
#pragma unroll
                for (int tr = 0; tr < 2; ++tr)
                    af[ab][tr] = *(const bf16x8*)((const char*)lAf +
                                 (((tr << 6) + k16n) << 10) + ((lane ^ (k16n & 7)) << 4));
            }
            // mid-section: convert + ds_write staged chunk c+1
            if (j == 7 && c < 3) {
#pragma unroll
                for (int it = 0; it < 4; ++it) {
                    const int k0 = kbase + ((((c + 1) << 2) + it) << 6);
                    bf16x8 c8;
                    c8[0] = (short)f2bf(g0[it][0]); c8[1] = (short)f2bf(g0[it][1]);
                    c8[2] = (short)f2bf(g0[it][2]); c8[3] = (short)f2bf(g0[it][3]);
                    c8[4] = (short)f2bf(g1[it][0]); c8[5] = (short)f2bf(g1[it][1]);
                    c8[6] = (short)f2bf(g1[it][2]); c8[7] = (short)f2bf(g1[it][3]);
                    const int k16 = k0 >> 4, hh = (k0 >> 3) & 1;
                    const int slot = ((hh << 5) + rml) ^ (k16 & 7);
                    *(bf16x8*)((char*)lAf + (((rt << 6) + k16) << 10) + (slot << 4)) = c8;
                }
            }
        }
        if (c < 3) {
            asm volatile("s_waitcnt lgkmcnt(0)" ::: "memory");
            __builtin_amdgcn_s_barrier();
            __builtin_amdgcn_sched_barrier(0);
        }
    }

    // ---- epilogue: fused RMSNorm ----
    // C/D layout (32x32): col = lane&31, row = (r&3) + 8*(r>>2) + 4*(lane>>5)
#pragma unroll
    for (int tr = 0; tr < 2; ++tr) {
#pragma unroll
        for (int r = 0; r < 16; ++r) {
            float v = 0.f;
#pragma unroll
            for (int tc = 0; tc < 4; ++tc) { float a = acc[tr][tc][r]; v += a * a; }
#pragma unroll
            for (int m = 1; m <= 16; m <<= 1) v += __shfl_xor(v, m, 64);
            if (ml == 0)
                atomicAdd(&rowss[tr * 32 + (r & 3) + 8 * (r >> 2) + 4 * h], v);
        }
    }
    __syncthreads();
    if (tid < MTILE) rowss[tid] = rsqrtf(rowss[tid] * (1.0f / 1024.0f) + 1e-6f);
    __syncthreads();

    float nwv[4];
#pragma unroll
    for (int tc = 0; tc < 4; ++tc) nwv[tc] = nw[(wv << 7) + tc * 32 + ml];

#pragma unroll
    for (int tr = 0; tr < 2; ++tr) {
#pragma unroll
        for (int r = 0; r < 16; ++r) {
            const int m = tr * 32 + (r & 3) + 8 * (r >> 2) + 4 * h;
            const float rs = rowss[m];
            float* orow = out + (size_t)(row0 + m) * NDIM + (wv << 7) + ml;
#pragma unroll
            for (int tc = 0; tc < 4; ++tc)
                __builtin_nontemporal_store(acc[tr][tc][r] * rs * nwv[tc], orow + tc * 32);
        }
    }
}

extern "C" void kernel_launch(void* const* d_in, const int* in_sizes, int n_in,
                              void* d_out, int out_size, void* d_ws, size_t ws_size,
                              hipStream_t stream) {
    const float* x  = (const float*)d_in[0];
    const float* cw = (const float*)d_in[1];
    const float* nw = (const float*)d_in[2];
    float* out = (float*)d_out;
    unsigned short* Wf = (unsigned short*)d_ws;   // 2 MB fragment-major W

    void* args[] = {(void*)&x, (void*)&cw, (void*)&nw, (void*)&out, (void*)&Wf};
    hipLaunchCooperativeKernel((const void*)fused_kernel, dim3(256), dim3(512),
                               args, 0, stream);
}

// Round 6
// 237.977 us; speedup vs baseline: 1.4904x; 1.4904x over previous
//
#include <hip/hip_runtime.h>

// ---------------------------------------------------------------------------
// Conv2DQwenRMSNorm: y = x @ W^T, W = mean_l(conv_w); RMSNorm(y)*norm_w.
// B=4,S=4096 -> M=16384; H=1024 (N=K).
//
// R9: evidence: R4/R5/R6 (3 schedules) and R7 (2x occupancy, 2x B-demand)
// all ~64us => per-wave VMEM-latency bound in the K-loop, no throughput
// ceiling. Fix: canonical LDS-staged GEMM (guide §5):
//  - W staged through LDS in 32 K-windows (WK=32), double-buffered,
//    via global_load_lds width=16 (bulk, vmcnt-counted, no per-wave
//    latency exposure in the MFMA loop)
//  - windows are time-correlated across all 256 blocks -> each 64KB
//    W-window is L2-hot broadcast (kills the decorrelation pathology too)
//  - inner loop = ds_read_b128 + MFMA only (lgkm waits, proven pattern)
//  - wprep writes W frag-major in k16-major order so a window is one
//    contiguous 64KB slice (linear global_load_lds both sides)
// LDS: lB 2x64KB + lA 2x4KB = 136KB; 1 block/CU, 8 waves.
// Epilogue / acc / fragment conventions identical to the proven kernel.
// ---------------------------------------------------------------------------

using bf16x8 = __attribute__((ext_vector_type(8))) short;
using f32x16 = __attribute__((ext_vector_type(16))) float;
using f32x4  = __attribute__((ext_vector_type(4))) float;

#define NDIM 1024
#define MTILE 64
#define NWIN 32

__device__ __forceinline__ unsigned short f2bf(float f) {
    unsigned u = __float_as_uint(f);
    u += 0x7fffu + ((u >> 16) & 1u);          // RNE
    return (unsigned short)(u >> 16);
}

__device__ __forceinline__ void gload_lds16(const void* g, void* l) {
    __builtin_amdgcn_global_load_lds(
        (const __attribute__((address_space(1))) unsigned int*)g,
        (__attribute__((address_space(3))) unsigned int*)l, 16, 0, 0);
}

// ---- Kernel 1: W = mean_l conv_w, bf16, fragment-major (k16-major) --------
__global__ __launch_bounds__(256) void wprep_kernel(const float* __restrict__ cw,
                                                    unsigned short* __restrict__ Wf) {
    const int idx = blockIdx.x * 256 + threadIdx.x;  // 0..262143
    const int o   = idx >> 8;                        // row 0..1023
    const int q   = idx & 255;                       // float4 index in row
    const float* p = cw + (size_t)o * NDIM + (q << 2);
    f32x4 s = {0.f, 0.f, 0.f, 0.f};
#pragma unroll
    for (int l = 0; l < 20; ++l) {
        f32x4 v = __builtin_nontemporal_load((const f32x4*)(p + (size_t)l * (NDIM * NDIM)));
        s += v;
    }
    const float sc = 0.05f;                          // 1/L
    ushort4 o4;
    o4.x = f2bf(s[0] * sc); o4.y = f2bf(s[1] * sc);
    o4.z = f2bf(s[2] * sc); o4.w = f2bf(s[3] * sc);
    const int ct  = o >> 5, ml = o & 31;
    const int k16 = q >> 2, h = (q >> 1) & 1, half = q & 1;
    // k16-major frag layout: frag(k16,ct) at (k16*32+ct)*1KB;
    // slot lane=(h*32+ml) holds W[ct*32+ml][k16*16+h*8..+7]
    *(ushort4*)((char*)Wf + (((k16 << 5) + ct) << 10) + (((h << 5) + ml) << 4) + (half << 3)) = o4;
}

// ---- Kernel 2: fused GEMM + RMSNorm ---------------------------------------
__global__ __launch_bounds__(512, 2) void gemm_rms_kernel(
        const float* __restrict__ x, const unsigned short* __restrict__ Wf,
        const float* __restrict__ nw, float* __restrict__ out) {
    __shared__ short lB[2][64][512];                 // 128 KB: [buf][k2*32+ct][slot*8]
    __shared__ short lA[2][4][512];                  // 8 KB:   [buf][rt*2+k2][slot*8]
    __shared__ float rowss[MTILE];

    const int tid  = threadIdx.x;
    const int wv   = tid >> 6;                       // 0..7
    const int lane = tid & 63;
    const int ml   = lane & 31;
    const int h    = lane >> 5;
    const int row0 = blockIdx.x * MTILE;

    if (tid < MTILE) rowss[tid] = 0.f;

    char* lBc = (char*)&lB[0][0][0];
    char* lAc = (char*)&lA[0][0][0];

    // A-staging geometry (waves 0-3 only): frag f = wv = rt*2+k2
    const int rt_s = wv >> 1, k2_s = wv & 1;
    const float* axp = x + (size_t)(row0 + (rt_s << 5) + ml) * NDIM + (k2_s << 4) + (h << 3);

    // W-staging: wave wv covers bytes [wv*8KB, wv*8KB+8KB) of each 64KB window
    const char* wsrc0 = (const char*)Wf + (wv << 13) + (lane << 4);

    // ---- prologue: stage window 0 into buf 0 ----
#pragma unroll
    for (int j = 0; j < 8; ++j)
        gload_lds16(wsrc0 + (j << 10), lBc + (wv << 13) + (j << 10));
    if (wv < 4) {
        f32x4 v0 = __builtin_nontemporal_load((const f32x4*)axp);
        f32x4 v1 = __builtin_nontemporal_load((const f32x4*)(axp + 4));
        bf16x8 c8;
        c8[0] = (short)f2bf(v0[0]); c8[1] = (short)f2bf(v0[1]);
        c8[2] = (short)f2bf(v0[2]); c8[3] = (short)f2bf(v0[3]);
        c8[4] = (short)f2bf(v1[0]); c8[5] = (short)f2bf(v1[1]);
        c8[6] = (short)f2bf(v1[2]); c8[7] = (short)f2bf(v1[3]);
        *(bf16x8*)(lAc + (wv << 10) + (lane << 4)) = c8;
    }
    __syncthreads();

    f32x16 acc[2][4];
#pragma unroll
    for (int tr = 0; tr < 2; ++tr)
#pragma unroll
        for (int tc = 0; tc < 4; ++tc)
#pragma unroll
            for (int r = 0; r < 16; ++r) acc[tr][tc][r] = 0.f;

    // ---- main loop: 32 windows of WK=32 (2 k16-frags) ----
#pragma unroll 1
    for (int w = 0; w < NWIN; ++w) {
        const int d  = w & 1;
        const int dn = d ^ 1;

        // issue next-window staging first (loads fly during compute)
        f32x4 v0, v1;
        if (w + 1 < NWIN) {
            const char* wsrc = wsrc0 + ((size_t)(w + 1) << 16);
#pragma unroll
            for (int j = 0; j < 8; ++j)
                gload_lds16(wsrc + (j << 10), lBc + (dn << 16) + (wv << 13) + (j << 10));
            if (wv < 4) {
                v0 = __builtin_nontemporal_load((const f32x4*)(axp + ((w + 1) << 5)));
                v1 = __builtin_nontemporal_load((const f32x4*)(axp + ((w + 1) << 5) + 4));
            }
        }

        // compute window w from buffer d: 2 k16-steps x 8 MFMA
#pragma unroll
        for (int k2 = 0; k2 < 2; ++k2) {
            bf16x8 a0 = *(const bf16x8*)(lAc + (d << 12) + (k2 << 10) + (lane << 4));
            bf16x8 a1 = *(const bf16x8*)(lAc + (d << 12) + ((2 + k2) << 10) + (lane << 4));
            const char* bbase = lBc + (d << 16) + (((k2 << 5) + (wv << 2)) << 10) + (lane << 4);
            bf16x8 b0 = *(const bf16x8*)(bbase);
            bf16x8 b1 = *(const bf16x8*)(bbase + (1 << 10));
            bf16x8 b2 = *(const bf16x8*)(bbase + (2 << 10));
            bf16x8 b3 = *(const bf16x8*)(bbase + (3 << 10));
            __builtin_amdgcn_s_setprio(1);
            acc[0][0] = __builtin_amdgcn_mfma_f32_32x32x16_bf16(a0, b0, acc[0][0], 0, 0, 0);
            acc[0][1] = __builtin_amdgcn_mfma_f32_32x32x16_bf16(a0, b1, acc[0][1], 0, 0, 0);
            acc[0][2] = __builtin_amdgcn_mfma_f32_32x32x16_bf16(a0, b2, acc[0][2], 0, 0, 0);
            acc[0][3] = __builtin_amdgcn_mfma_f32_32x32x16_bf16(a0, b3, acc[0][3], 0, 0, 0);
            acc[1][0] = __builtin_amdgcn_mfma_f32_32x32x16_bf16(a1, b0, acc[1][0], 0, 0, 0);
            acc[1][1] = __builtin_amdgcn_mfma_f32_32x32x16_bf16(a1, b1, acc[1][1], 0, 0, 0);
            acc[1][2] = __builtin_amdgcn_mfma_f32_32x32x16_bf16(a1, b2, acc[1][2], 0, 0, 0);
            acc[1][3] = __builtin_amdgcn_mfma_f32_32x32x16_bf16(a1, b3, acc[1][3], 0, 0, 0);
            __builtin_amdgcn_s_setprio(0);
        }

        // A-window w+1: convert + ds_write (loads have landed by now)
        if (w + 1 < NWIN && wv < 4) {
            bf16x8 c8;
            c8[0] = (short)f2bf(v0[0]); c8[1] = (short)f2bf(v0[1]);
            c8[2] = (short)f2bf(v0[2]); c8[3] = (short)f2bf(v0[3]);
            c8[4] = (short)f2bf(v1[0]); c8[5] = (short)f2bf(v1[1]);
            c8[6] = (short)f2bf(v1[2]); c8[7] = (short)f2bf(v1[3]);
            *(bf16x8*)(lAc + (dn << 12) + (wv << 10) + (lane << 4)) = c8;
        }
        __syncthreads();   // drains vmcnt (global_load_lds) + lgkm (ds_write)
    }

    // ---- epilogue: fused RMSNorm (unchanged, proven) ----
    // C/D layout (32x32): col = lane&31, row = (r&3) + 8*(r>>2) + 4*(lane>>5)
#pragma unroll
    for (int tr = 0; tr < 2; ++tr) {
#pragma unroll
        for (int r = 0; r < 16; ++r) {
            float v = 0.f;
#pragma unroll
            for (int tc = 0; tc < 4; ++tc) { float a = acc[tr][tc][r]; v += a * a; }
#pragma unroll
            for (int m = 1; m <= 16; m <<= 1) v += __shfl_xor(v, m, 64);
            if (ml == 0)
                atomicAdd(&rowss[tr * 32 + (r & 3) + 8 * (r >> 2) + 4 * h], v);
        }
    }
    __syncthreads();
    if (tid < MTILE) rowss[tid] = rsqrtf(rowss[tid] * (1.0f / 1024.0f) + 1e-6f);
    __syncthreads();

    float nwv[4];
#pragma unroll
    for (int tc = 0; tc < 4; ++tc) nwv[tc] = nw[(wv << 7) + tc * 32 + ml];

#pragma unroll
    for (int tr = 0; tr < 2; ++tr) {
#pragma unroll
        for (int r = 0; r < 16; ++r) {
            const int m = tr * 32 + (r & 3) + 8 * (r >> 2) + 4 * h;
            const float rs = rowss[m];
            float* orow = out + (size_t)(row0 + m) * NDIM + (wv << 7) + ml;
#pragma unroll
            for (int tc = 0; tc < 4; ++tc)
                __builtin_nontemporal_store(acc[tc == 0 ? tr : tr][tc][r] * rs * nwv[tc], orow + tc * 32);
        }
    }
}

extern "C" void kernel_launch(void* const* d_in, const int* in_sizes, int n_in,
                              void* d_out, int out_size, void* d_ws, size_t ws_size,
                              hipStream_t stream) {
    const float* x  = (const float*)d_in[0];
    const float* cw = (const float*)d_in[1];
    const float* nw = (const float*)d_in[2];
    float* out = (float*)d_out;
    unsigned short* Wf = (unsigned short*)d_ws;   // 2 MB fragment-major W (k16-major)

    hipLaunchKernelGGL(wprep_kernel, dim3(1024), dim3(256), 0, stream, cw, Wf);
    hipLaunchKernelGGL(gemm_rms_kernel, dim3(256), dim3(512), 0, stream, x, Wf, nw, out);
}

// Round 7
// 216.202 us; speedup vs baseline: 1.6406x; 1.1007x over previous
//
#include <hip/hip_runtime.h>

// ---------------------------------------------------------------------------
// Conv2DQwenRMSNorm: y = x @ W^T, W = mean_l(conv_w); RMSNorm(y)*norm_w.
// B=4,S=4096 -> M=16384; H=1024 (N=K).
//
// R10: single-variable A/B vs R6 (64.0us): phase stagger REMOVED (phase=0).
// Evidence: R9's bulk-DMA structure measured ~30 GB/s/CU B-delivery =
// 512 MB aggregate W re-reads at ~7 TB/s == the entire kernel duration in
// every round. The blockIdx*37 K-phase stagger decorrelates the 32 blocks
// per XCD, so W (2MB, fits 4MB L2) is evicted by the x/out stream between
// touches -> every B-read goes to L3. In-phase sweep (R7 showed co-resident
// sharing works) makes each W line L2-hot for the whole 32-CU cohort.
// Everything else is byte-identical to R6.
// ---------------------------------------------------------------------------

using bf16x8 = __attribute__((ext_vector_type(8))) short;
using f32x16 = __attribute__((ext_vector_type(16))) float;
using f32x4  = __attribute__((ext_vector_type(4))) float;

#define NDIM 1024
#define MTILE 64

__device__ __forceinline__ unsigned short f2bf(float f) {
    unsigned u = __float_as_uint(f);
    u += 0x7fffu + ((u >> 16) & 1u);          // RNE
    return (unsigned short)(u >> 16);
}

// ---- Kernel 1: W = mean_l conv_w, bf16, fragment-major ---------------------
__global__ __launch_bounds__(256) void wprep_kernel(const float* __restrict__ cw,
                                                    unsigned short* __restrict__ Wf) {
    const int idx = blockIdx.x * 256 + threadIdx.x;  // 0..262143
    const int o   = idx >> 8;                        // row 0..1023
    const int q   = idx & 255;                       // float4 index in row
    const float* p = cw + (size_t)o * NDIM + (q << 2);
    f32x4 s = {0.f, 0.f, 0.f, 0.f};
#pragma unroll
    for (int l = 0; l < 20; ++l) {
        f32x4 v = __builtin_nontemporal_load((const f32x4*)(p + (size_t)l * (NDIM * NDIM)));
        s += v;
    }
    const float sc = 0.05f;                          // 1/L
    ushort4 o4;
    o4.x = f2bf(s[0] * sc); o4.y = f2bf(s[1] * sc);
    o4.z = f2bf(s[2] * sc); o4.w = f2bf(s[3] * sc);
    const int ct  = o >> 5, ml = o & 31;
    const int k16 = q >> 2, h = (q >> 1) & 1, half = q & 1;
    // frag-major: frag(ct,k16)=1KB; slot lane=(h*32+ml) holds W[ct*32+ml][k16*16+h*8..+7]
    *(ushort4*)((char*)Wf + (((ct << 6) + k16) << 10) + (((h << 5) + ml) << 4) + (half << 3)) = o4;
}

// ---- Kernel 2: fused GEMM + RMSNorm ---------------------------------------
__global__ __launch_bounds__(512, 2) void gemm_rms_kernel(
        const float* __restrict__ x, const unsigned short* __restrict__ Wf,
        const float* __restrict__ nw, float* __restrict__ out) {
    __shared__ short lAf[MTILE * NDIM];              // 128 KB, frag-major
    __shared__ float rowss[MTILE];

    const int tid  = threadIdx.x;
    const int wv   = tid >> 6;                       // 0..7
    const int lane = tid & 63;
    const int ml   = lane & 31;
    const int h    = lane >> 5;
    const int row0 = blockIdx.x * MTILE;
    const int phase = 0;                             // R10: in-phase W sweep (was blockIdx*37)

    if (tid < MTILE) rowss[tid] = 0.f;

    // staging geometry (all 512 threads): row = tid>>3, 8-elem cols by tid&7
    const int row = tid >> 3;                        // 0..63
    const int rt  = row >> 5, rml = row & 31;
    const float* xr = x + (size_t)(row0 + row) * NDIM;
    const int kbase = (tid & 7) << 3;

    // B bases: wave wv owns column-tiles ct = wv*4 .. wv*4+3
    const char* bB[4];
#pragma unroll
    for (int c = 0; c < 4; ++c)
        bB[c] = (const char*)Wf + ((((wv << 2) + c) << 6) << 10) + (lane << 4);

    // ---- warm B FIFO (depth 2) for i = 0,1
    bf16x8 bfr[2][4];
#pragma unroll
    for (int d = 0; d < 2; ++d) {
        const int k16 = (d + phase) & 15;            // section 0
#pragma unroll
        for (int cc = 0; cc < 4; ++cc)
            bfr[d][cc] = *(const bf16x8*)(bB[cc] + (k16 << 10));
    }

    // ---- prologue: stage chunk 0 only (64 rows x 256 k, fp32->bf16) ----
#pragma unroll
    for (int it = 0; it < 4; ++it) {
        const int k0 = kbase + (it << 6);
        f32x4 v0 = __builtin_nontemporal_load((const f32x4*)(xr + k0));
        f32x4 v1 = __builtin_nontemporal_load((const f32x4*)(xr + k0 + 4));
        bf16x8 c8;
        c8[0] = (short)f2bf(v0[0]); c8[1] = (short)f2bf(v0[1]);
        c8[2] = (short)f2bf(v0[2]); c8[3] = (short)f2bf(v0[3]);
        c8[4] = (short)f2bf(v1[0]); c8[5] = (short)f2bf(v1[1]);
        c8[6] = (short)f2bf(v1[2]); c8[7] = (short)f2bf(v1[3]);
        const int k16 = k0 >> 4, hh = (k0 >> 3) & 1;
        const int slot = ((hh << 5) + rml) ^ (k16 & 7);
        *(bf16x8*)((char*)lAf + (((rt << 6) + k16) << 10) + (slot << 4)) = c8;
    }
    __syncthreads();

    f32x16 acc[2][4];
#pragma unroll
    for (int tr = 0; tr < 2; ++tr)
#pragma unroll
        for (int tc = 0; tc < 4; ++tc)
#pragma unroll
            for (int r = 0; r < 16; ++r) acc[tr][tc][r] = 0.f;

    bf16x8 af[2][2];

    // ---- pipelined K loop: 4 sections x 16 iters; section c computes chunk c
    //      while staging chunk c+1 ----
#pragma unroll
    for (int c = 0; c < 4; ++c) {
        // issue global loads for chunk c+1 ASAP (consumed at j==7)
        f32x4 g0[4], g1[4];
        if (c < 3) {
#pragma unroll
            for (int it = 0; it < 4; ++it) {
                const int k0 = kbase + ((((c + 1) << 2) + it) << 6);
                g0[it] = __builtin_nontemporal_load((const f32x4*)(xr + k0));
                g1[it] = __builtin_nontemporal_load((const f32x4*)(xr + k0 + 4));
            }
        }
        // A warm for j = 0,1 of this section (chunk c is barrier-synced)
#pragma unroll
        for (int d = 0; d < 2; ++d) {
            const int k16 = (c << 4) + ((d + phase) & 15);
#pragma unroll
            for (int tr = 0; tr < 2; ++tr)
                af[d][tr] = *(const bf16x8*)((const char*)lAf +
                            (((tr << 6) + k16) << 10) + ((lane ^ (k16 & 7)) << 4));
        }

#pragma unroll
        for (int j = 0; j < 16; ++j) {
            const int i  = (c << 4) + j;
            const int ab = j & 1, bb = i & 1;
            __builtin_amdgcn_s_setprio(1);
            acc[0][0] = __builtin_amdgcn_mfma_f32_32x32x16_bf16(af[ab][0], bfr[bb][0], acc[0][0], 0, 0, 0);
            acc[0][1] = __builtin_amdgcn_mfma_f32_32x32x16_bf16(af[ab][0], bfr[bb][1], acc[0][1], 0, 0, 0);
            acc[0][2] = __builtin_amdgcn_mfma_f32_32x32x16_bf16(af[ab][0], bfr[bb][2], acc[0][2], 0, 0, 0);
            acc[0][3] = __builtin_amdgcn_mfma_f32_32x32x16_bf16(af[ab][0], bfr[bb][3], acc[0][3], 0, 0, 0);
            acc[1][0] = __builtin_amdgcn_mfma_f32_32x32x16_bf16(af[ab][1], bfr[bb][0], acc[1][0], 0, 0, 0);
            acc[1][1] = __builtin_amdgcn_mfma_f32_32x32x16_bf16(af[ab][1], bfr[bb][1], acc[1][1], 0, 0, 0);
            acc[1][2] = __builtin_amdgcn_mfma_f32_32x32x16_bf16(af[ab][1], bfr[bb][2], acc[1][2], 0, 0, 0);
            acc[1][3] = __builtin_amdgcn_mfma_f32_32x32x16_bf16(af[ab][1], bfr[bb][3], acc[1][3], 0, 0, 0);
            __builtin_amdgcn_s_setprio(0);
            // B refill (consume-then-refill, distance 2, crosses sections)
            if (i + 2 < 64) {
                const int i2 = i + 2;
                const int k16n = (i2 & ~15) + (((i2 & 15) + phase) & 15);
#pragma unroll
                for (int cc = 0; cc < 4; ++cc)
                    bfr[bb][cc] = *(const bf16x8*)(bB[cc] + (k16n << 10));
            }
            // A refill (distance 2, within section only — chunk c is synced)
            if (j + 2 < 16) {
                const int k16n = (c << 4) + (((j + 2) + phase) & 15);
#pragma unroll
                for (int tr = 0; tr < 2; ++tr)
                    af[ab][tr] = *(const bf16x8*)((const char*)lAf +
                                 (((tr << 6) + k16n) << 10) + ((lane ^ (k16n & 7)) << 4));
            }
            // mid-section: convert + ds_write staged chunk c+1
            if (j == 7 && c < 3) {
#pragma unroll
                for (int it = 0; it < 4; ++it) {
                    const int k0 = kbase + ((((c + 1) << 2) + it) << 6);
                    bf16x8 c8;
                    c8[0] = (short)f2bf(g0[it][0]); c8[1] = (short)f2bf(g0[it][1]);
                    c8[2] = (short)f2bf(g0[it][2]); c8[3] = (short)f2bf(g0[it][3]);
                    c8[4] = (short)f2bf(g1[it][0]); c8[5] = (short)f2bf(g1[it][1]);
                    c8[6] = (short)f2bf(g1[it][2]); c8[7] = (short)f2bf(g1[it][3]);
                    const int k16 = k0 >> 4, hh = (k0 >> 3) & 1;
                    const int slot = ((hh << 5) + rml) ^ (k16 & 7);
                    *(bf16x8*)((char*)lAf + (((rt << 6) + k16) << 10) + (slot << 4)) = c8;
                }
            }
        }
        // section barrier: lgkm drain only (B prefetches stay in flight)
        if (c < 3) {
            asm volatile("s_waitcnt lgkmcnt(0)" ::: "memory");
            __builtin_amdgcn_s_barrier();
            __builtin_amdgcn_sched_barrier(0);
        }
    }

    // ---- epilogue: fused RMSNorm ----
    // C/D layout (32x32): col = lane&31, row = (r&3) + 8*(r>>2) + 4*(lane>>5)
#pragma unroll
    for (int tr = 0; tr < 2; ++tr) {
#pragma unroll
        for (int r = 0; r < 16; ++r) {
            float v = 0.f;
#pragma unroll
            for (int tc = 0; tc < 4; ++tc) { float a = acc[tr][tc][r]; v += a * a; }
#pragma unroll
            for (int m = 1; m <= 16; m <<= 1) v += __shfl_xor(v, m, 64);
            if (ml == 0)
                atomicAdd(&rowss[tr * 32 + (r & 3) + 8 * (r >> 2) + 4 * h], v);
        }
    }
    __syncthreads();
    if (tid < MTILE) rowss[tid] = rsqrtf(rowss[tid] * (1.0f / 1024.0f) + 1e-6f);
    __syncthreads();

    float nwv[4];
#pragma unroll
    for (int tc = 0; tc < 4; ++tc) nwv[tc] = nw[(wv << 7) + tc * 32 + ml];

#pragma unroll
    for (int tr = 0; tr < 2; ++tr) {
#pragma unroll
        for (int r = 0; r < 16; ++r) {
            const int m = tr * 32 + (r & 3) + 8 * (r >> 2) + 4 * h;
            const float rs = rowss[m];
            float* orow = out + (size_t)(row0 + m) * NDIM + (wv << 7) + ml;
#pragma unroll
            for (int tc = 0; tc < 4; ++tc)
                __builtin_nontemporal_store(acc[tr][tc][r] * rs * nwv[tc], orow + tc * 32);
        }
    }
}

extern "C" void kernel_launch(void* const* d_in, const int* in_sizes, int n_in,
                              void* d_out, int out_size, void* d_ws, size_t ws_size,
                              hipStream_t stream) {
    const float* x  = (const float*)d_in[0];
    const float* cw = (const float*)d_in[1];
    const float* nw = (const float*)d_in[2];
    float* out = (float*)d_out;
    unsigned short* Wf = (unsigned short*)d_ws;   // 2 MB fragment-major W

    hipLaunchKernelGGL(wprep_kernel, dim3(1024), dim3(256), 0, stream, cw, Wf);
    hipLaunchKernelGGL(gemm_rms_kernel, dim3(256), dim3(512), 0, stream, x, Wf, nw, out);
}